// Round 1
// baseline (322.395 us; speedup 1.0000x reference)
//
#include <hip/hip_runtime.h>
#include <math.h>

// Caps1D dynamic routing.
// u: [B=1024, R=2336, M=4] fp32 ; W: [K=2, R=2336, M=4, P=16] fp32
// out: classes [B, K] fp32 = norm/(1+norm) of final squash input.
//
// One block per (b,k). u_ji[r,0..15] lives in registers, distributed over
// 512 threads x 5 rows (r = tid + j*512). Routing iterations are block
// reductions (wave shuffle + LDS) — W/u are read from global exactly once.

#define THREADS 512
#define ROWS 5            // ceil(2336 / 512)

__global__ __launch_bounds__(THREADS, 2)
void caps_routing_kernel(const float* __restrict__ u,
                         const float* __restrict__ W,
                         float* __restrict__ out)
{
    constexpr int B = 1024, K = 2, R = 2336, P = 16;

    const int bi   = blockIdx.x;
    const int b    = bi >> 1;
    const int k    = bi & 1;
    const int tid  = threadIdx.x;
    const int lane = tid & 63;
    const int wave = tid >> 6;

    __shared__ float redmax[8];
    __shared__ float red[8][17];   // 16 s-partials + sumexp per wave
    __shared__ float vbuf[P];

    const float4* __restrict__ u4 = (const float4*)u;
    const float4* __restrict__ w4 = (const float4*)W;

    float uji[ROWS][P];
    float brow[ROWS];
    bool  valid[ROWS];

    // ---- build u_ji = u[b,r,:] @ W[k,r,:,:]  (M=4 contraction) ----
    #pragma unroll
    for (int j = 0; j < ROWS; ++j) {
        const int r = tid + j * THREADS;
        valid[j] = (r < R);
        brow[j]  = valid[j] ? 0.0f : -INFINITY;
        #pragma unroll
        for (int p = 0; p < P; ++p) uji[j][p] = 0.0f;
        if (valid[j]) {
            float4 uu = u4[b * R + r];                 // u[b,r,0..3]
            float um[4] = {uu.x, uu.y, uu.z, uu.w};
            const int wbase = (k * R + r) * 16;        // float4 index into W row (64 floats)
            #pragma unroll
            for (int m = 0; m < 4; ++m) {
                #pragma unroll
                for (int q = 0; q < 4; ++q) {
                    float4 w = w4[wbase + m * 4 + q];
                    uji[j][q * 4 + 0] += um[m] * w.x;
                    uji[j][q * 4 + 1] += um[m] * w.y;
                    uji[j][q * 4 + 2] += um[m] * w.z;
                    uji[j][q * 4 + 3] += um[m] * w.w;
                }
            }
        }
    }

    // ---- 3 routing iterations ----
    for (int it = 0; it < 3; ++it) {
        // block max of logits (softmax stability, matches jax.nn.softmax)
        float mloc = -INFINITY;
        #pragma unroll
        for (int j = 0; j < ROWS; ++j) mloc = fmaxf(mloc, brow[j]);
        #pragma unroll
        for (int o = 32; o > 0; o >>= 1) mloc = fmaxf(mloc, __shfl_down(mloc, o));
        if (lane == 0) redmax[wave] = mloc;
        __syncthreads();
        float bmax = redmax[0];
        #pragma unroll
        for (int w = 1; w < 8; ++w) bmax = fmaxf(bmax, redmax[w]);

        // fused exp + weighted sums: s_p = sum_r e_r * uji[r,p], se = sum_r e_r
        float sloc[P];
        #pragma unroll
        for (int p = 0; p < P; ++p) sloc[p] = 0.0f;
        float seloc = 0.0f;
        #pragma unroll
        for (int j = 0; j < ROWS; ++j) {
            float e = valid[j] ? __expf(brow[j] - bmax) : 0.0f;
            seloc += e;
            #pragma unroll
            for (int p = 0; p < P; ++p) sloc[p] += e * uji[j][p];
        }
        #pragma unroll
        for (int o = 32; o > 0; o >>= 1) {
            seloc += __shfl_down(seloc, o);
            #pragma unroll
            for (int p = 0; p < P; ++p) sloc[p] += __shfl_down(sloc[p], o);
        }
        if (lane == 0) {
            #pragma unroll
            for (int p = 0; p < P; ++p) red[wave][p] = sloc[p];
            red[wave][16] = seloc;
        }
        __syncthreads();

        // thread 0: finish reduction, squash, stash v (and final output)
        if (tid == 0) {
            float se = 0.0f;
            #pragma unroll
            for (int w = 0; w < 8; ++w) se += red[w][16];
            float inv_se = 1.0f / se;
            float norm = 0.0f;
            float s[P];
            #pragma unroll
            for (int p = 0; p < P; ++p) {
                float acc = 0.0f;
                #pragma unroll
                for (int w = 0; w < 8; ++w) acc += red[w][p];
                s[p] = acc * inv_se;
                norm += s[p] * s[p];
            }
            // squash: v = (norm/(1+norm)) * s / sqrt(norm) = s * sqrt(norm)/(1+norm)
            float f = sqrtf(norm) / (1.0f + norm);
            #pragma unroll
            for (int p = 0; p < P; ++p) vbuf[p] = f * s[p];
            if (it == 2) out[b * K + k] = norm / (1.0f + norm);  // |v| = scale
        }
        __syncthreads();

        // logit update: b_r += dot(u_ji[r,:], v)   (skipped on last iter)
        if (it < 2) {
            float v[P];
            #pragma unroll
            for (int p = 0; p < P; ++p) v[p] = vbuf[p];
            #pragma unroll
            for (int j = 0; j < ROWS; ++j) {
                float d = 0.0f;
                #pragma unroll
                for (int p = 0; p < P; ++p) d += uji[j][p] * v[p];
                brow[j] += d;
            }
        }
    }
}

extern "C" void kernel_launch(void* const* d_in, const int* in_sizes, int n_in,
                              void* d_out, int out_size, void* d_ws, size_t ws_size,
                              hipStream_t stream) {
    const float* u = (const float*)d_in[0];   // [1024, 2336, 4]
    const float* W = (const float*)d_in[1];   // [2, 2336, 4, 16]
    float* out = (float*)d_out;               // [1024, 2]
    caps_routing_kernel<<<dim3(2048), dim3(THREADS), 0, stream>>>(u, W, out);
}